// Round 5
// baseline (303.545 us; speedup 1.0000x reference)
//
#include <hip/hip_runtime.h>
#include <math.h>

// TriangleAttention round 5: k_attn occupancy + latency fixes.
// - no K LDS tile (K read once per j-tile -> direct global A-frags)
// - bias packed in MFMA-C order by k1 (coalesced 16B/lane loads), pre-scaled by log2e
// - q pre-scaled by log2e/sqrt(32) in k0; exp via exp2f (add+v_exp)
// - K/bias prefetched one j-iter ahead; halved wave-private P tile
// ws: qkvb bf16[NPOS][384] | attb bf16[NPOS][128] | wT bf16[640][128] |
//     gateb bf16[NPOS][128] | biasX bf16[4][NPOS] (packed)

#define LL 320
#define CC 128
#define NPOS (LL*LL)

typedef __attribute__((ext_vector_type(8))) __bf16 bf16x8;
typedef __attribute__((ext_vector_type(4))) __bf16 bf16x4;
typedef __attribute__((ext_vector_type(4))) float f32x4;

#define MFMA16(a,b,c) __builtin_amdgcn_mfma_f32_16x16x32_bf16(a,b,c,0,0,0)

// XOR swizzle for 128x128 bf16 GEMM tiles (k1/k3)
__device__ __forceinline__ int swz(int m, int kc) {
    return m*128 + ((kc ^ (m & 7)) << 3);
}

// ---------------- k0: weights -> bf16, transposed [n][k] ----------------
// rows 0..383 WqkvT (q cols scaled by log2e/sqrt(32)), 384..511 WgateT, 512..639 WoutT
__global__ __launch_bounds__(128) void k_wprep(
    const float* __restrict__ Wqkv, const float* __restrict__ Wgate,
    const float* __restrict__ Wout, __bf16* __restrict__ wT)
{
    const int n = blockIdx.x, t = threadIdx.x;
    float v;
    if (n < 384)      v = Wqkv[(size_t)t*384 + n] * (n < 128 ? 0.25508635f : 1.f);
    else if (n < 512) v = Wgate[(size_t)t*128 + (n-384)];
    else              v = Wout[(size_t)t*128 + (n-512)];
    wT[(size_t)n*128 + t] = (__bf16)v;
}

// ---------------- k1: LN + projections (MFMA) ----------------
// grid 800, block 512 (8 waves). Per block: 128-row M-tile; loop 4 N-chunks
// (qkv0/qkv1/qkv2/gate). Pair bias computed from fp32 LN regs, written in
// packed MFMA-C order: biasX[h][(j/32)*320 + i][quad*8 + mt*4 + reg], *log2e.
__global__ __launch_bounds__(512) void k_ln_proj(
    const float* __restrict__ z, const float* __restrict__ lng, const float* __restrict__ lnb,
    const __bf16* __restrict__ wT, const float* __restrict__ Wpair,
    const float* __restrict__ bgate,
    __bf16* __restrict__ qkvb, __bf16* __restrict__ biasX, __bf16* __restrict__ gateb)
{
    __shared__ __bf16 As[128*128];
    __shared__ __bf16 Bs[128*128];
    const int t = threadIdx.x;
    const int posBase = blockIdx.x * 128;

    // --- LN 128 rows -> bf16 As (swizzled); pair projection from fp32 regs
    {
        const int r0 = t >> 2, q = t & 3;
        const float* zp = z + (size_t)(posBase + r0)*CC + q*32;
        float v[32];
        float s = 0.f, sq = 0.f;
#pragma unroll
        for (int i = 0; i < 8; ++i) {
            float4 f = ((const float4*)zp)[i];
            v[4*i+0]=f.x; v[4*i+1]=f.y; v[4*i+2]=f.z; v[4*i+3]=f.w;
            s  += f.x + f.y + f.z + f.w;
            sq += f.x*f.x + f.y*f.y + f.z*f.z + f.w*f.w;
        }
        s  += __shfl_xor(s, 1);  sq += __shfl_xor(sq, 1);
        s  += __shfl_xor(s, 2);  sq += __shfl_xor(sq, 2);
        const float mean = s * (1.f/128.f);
        const float var  = sq * (1.f/128.f) - mean*mean;
        const float rstd = rsqrtf(var + 1e-5f);
        const float4* g4 = (const float4*)(lng + q*32);
        const float4* b4 = (const float4*)(lnb + q*32);
#pragma unroll
        for (int i = 0; i < 8; ++i) {
            float4 gg = g4[i], bb = b4[i];
            v[4*i+0] = (v[4*i+0]-mean)*rstd*gg.x + bb.x;
            v[4*i+1] = (v[4*i+1]-mean)*rstd*gg.y + bb.y;
            v[4*i+2] = (v[4*i+2]-mean)*rstd*gg.z + bb.z;
            v[4*i+3] = (v[4*i+3]-mean)*rstd*gg.w + bb.w;
        }
#pragma unroll
        for (int i2 = 0; i2 < 8; ++i2) {
            bf16x4 pk;
            pk[0] = (__bf16)v[4*i2+0]; pk[1] = (__bf16)v[4*i2+1];
            pk[2] = (__bf16)v[4*i2+2]; pk[3] = (__bf16)v[4*i2+3];
            *(bf16x4*)&As[swz(r0, q*4 + (i2>>1)) + (i2&1)*4] = pk;
        }
        // pair: pc[c] = sum_k zn[k]*Wpair[k][c], partial over this thread's 32 k
        float pc0=0.f, pc1=0.f, pc2=0.f, pc3=0.f;
#pragma unroll 8
        for (int kk = 0; kk < 32; ++kk) {
            float4 wp = *(const float4*)&Wpair[(q*32 + kk)*4];
            pc0 += v[kk]*wp.x; pc1 += v[kk]*wp.y; pc2 += v[kk]*wp.z; pc3 += v[kk]*wp.w;
        }
        pc0 += __shfl_xor(pc0,1); pc0 += __shfl_xor(pc0,2);
        pc1 += __shfl_xor(pc1,1); pc1 += __shfl_xor(pc1,2);
        pc2 += __shfl_xor(pc2,1); pc2 += __shfl_xor(pc2,2);
        pc3 += __shfl_xor(pc3,1); pc3 += __shfl_xor(pc3,2);
        if (q == 0) {
            const int p = posBase + r0;
            const int i = p / 320, j = p - i*320;
            const int mt = (j >> 4) & 1, qd = (j >> 2) & 3, rg = j & 3;
            const size_t base = ((size_t)(j >> 5)*320 + i)*32 + qd*8 + mt*4 + rg;
            const float l2e = 1.4426950408889634f;
            biasX[0*(size_t)NPOS + base] = (__bf16)(pc0*l2e);
            biasX[1*(size_t)NPOS + base] = (__bf16)(pc1*l2e);
            biasX[2*(size_t)NPOS + base] = (__bf16)(pc2*l2e);
            biasX[3*(size_t)NPOS + base] = (__bf16)(pc3*l2e);
        }
    }

    const int lane = t & 63, wv = t >> 6;
    const int l15 = lane & 15, quad = lane >> 4;
    const int m0 = wv * 16;
    const int srow = t >> 2, skc0 = (t & 3) * 4;

    for (int ch = 0; ch < 4; ++ch) {
        __syncthreads();
        {   // stage B chunk: rows ch*128..+127 of wT
            const __bf16* src = wT + (size_t)(ch*128 + srow)*128;
#pragma unroll
            for (int j = 0; j < 4; ++j)
                *(bf16x8*)&Bs[swz(srow, skc0 + j)] = *(const bf16x8*)(src + (skc0 + j)*8);
        }
        __syncthreads();

        f32x4 acc[8] = {};
#pragma unroll
        for (int kstep = 0; kstep < 4; ++kstep) {
            bf16x8 aA = *(const bf16x8*)&As[swz(m0 + l15, kstep*4 + quad)];
#pragma unroll
            for (int nt = 0; nt < 8; ++nt) {
                bf16x8 bB = *(const bf16x8*)&Bs[swz(nt*16 + l15, kstep*4 + quad)];
                acc[nt] = MFMA16(aA, bB, acc[nt]);
            }
        }

        if (ch < 3) {
#pragma unroll
            for (int reg = 0; reg < 4; ++reg) {
                __bf16* qp = qkvb + (size_t)(posBase + m0 + quad*4 + reg)*384 + ch*128 + l15;
#pragma unroll
                for (int nt = 0; nt < 8; ++nt)
                    qp[nt*16] = (__bf16)acc[nt][reg];
            }
        } else {
#pragma unroll
            for (int reg = 0; reg < 4; ++reg) {
                __bf16* gp = gateb + (size_t)(posBase + m0 + quad*4 + reg)*128 + l15;
#pragma unroll
                for (int nt = 0; nt < 8; ++nt) {
                    float x = acc[nt][reg] + bgate[nt*16 + l15];
                    gp[nt*16] = (__bf16)(1.f/(1.f + __expf(-x)));
                }
            }
        }
    }
}

// ---------------- k2: MFMA flash attention, prefetched, low-LDS ----------------
// grid (320, 4) = (r, h). Block 320 = 5 waves; wave w owns i = w*64..+63.
// V^T staged in LDS once; K A-frags + packed bias read direct from global,
// prefetched one j-iter ahead. P round-trips through a 32-row wave-private
// LDS tile (two nt per step). Max-free softmax (exp2, inputs pre-scaled).
#define VT_ST 328   // V^T row stride (elems): 164 dwords -> 2-way banks
#define PW_ST 40    // P row stride
__global__ __launch_bounds__(320, 4) void k_attn(
    const __bf16* __restrict__ qkvb, const __bf16* __restrict__ biasX,
    const __bf16* __restrict__ gateb, __bf16* __restrict__ attb)
{
    __shared__ __bf16 Vt[32*VT_ST];        // V^T[d][j]   (20992 B)
    __shared__ __bf16 Pw[5][32*PW_ST];     // per-wave P  (12800 B)

    const int t = threadIdx.x, wave = t / 64, lane = t & 63;
    const int l15 = lane & 15, quad = lane >> 4;
    const int r = blockIdx.x, h = blockIdx.y;
    const int i0 = wave * 64;
    const size_t rowBase = (size_t)r * LL;

    // ---- one-time staging: V transpose (thread t handles j-row t)
    {
        const __bf16* vp = qkvb + (rowBase + t)*384 + 256 + h*32;
#pragma unroll
        for (int c = 0; c < 4; ++c) {
            bf16x8 vv = *(const bf16x8*)(vp + c*8);
#pragma unroll
            for (int e = 0; e < 8; ++e)
                Vt[(c*8 + e)*VT_ST + t] = vv[e];
        }
    }

    // Q B-fragments (4 i-subtiles); q pre-scaled by log2e/sqrt(32)
    bf16x8 qf[4];
#pragma unroll
    for (int nt = 0; nt < 4; ++nt)
        qf[nt] = *(const bf16x8*)(qkvb + (rowBase + i0 + nt*16 + l15)*384 + h*32 + quad*8);

    const __bf16* kbase = qkvb + rowBase*384 + 128 + h*32 + quad*8;   // + j*384
    const __bf16* bbase = biasX + (size_t)h*NPOS;                     // packed per h
    const size_t bofs0 = ((size_t)(i0 + l15))*32 + quad*8;            // + nt*16*32 + j0t*320*32

    // initial prefetch (j0 = 0)
    bf16x8 kf0 = *(const bf16x8*)(kbase + (size_t)(l15     )*384);
    bf16x8 kf1 = *(const bf16x8*)(kbase + (size_t)(16 + l15)*384);
    bf16x8 bf[4];
#pragma unroll
    for (int nt = 0; nt < 4; ++nt)
        bf[nt] = *(const bf16x8*)(bbase + bofs0 + nt*512);

    __syncthreads();   // Vt ready

    f32x4 O[4][2] = {};              // C layout: rows = i, cols(l15) = d
    float lp[4] = {0.f,0.f,0.f,0.f}; // per-lane partial row sums, i = i0+nt*16+l15
    __bf16* pw = &Pw[wave][0];

    for (int j0 = 0; j0 < LL; j0 += 32) {
        const bf16x8 kc0 = kf0, kc1 = kf1;
        bf16x8 bc[4] = {bf[0], bf[1], bf[2], bf[3]};
        if (j0 + 32 < LL) {   // prefetch next iter
            kf0 = *(const bf16x8*)(kbase + (size_t)(j0 + 32 + l15)*384);
            kf1 = *(const bf16x8*)(kbase + (size_t)(j0 + 48 + l15)*384);
            const size_t bo = bofs0 + (size_t)((j0 >> 5) + 1)*10240;
#pragma unroll
            for (int nt = 0; nt < 4; ++nt)
                bf[nt] = *(const bf16x8*)(bbase + bo + nt*512);
        }

        // S^T = K Q^T : C[m=j][n=i]; st0 = j0..j0+15 rows, st1 = +16
        const f32x4 zero = {0.f,0.f,0.f,0.f};
        f32x4 st0[4], st1[4];
#pragma unroll
        for (int nt = 0; nt < 4; ++nt) st0[nt] = MFMA16(kc0, qf[nt], zero);
#pragma unroll
        for (int nt = 0; nt < 4; ++nt) st1[nt] = MFMA16(kc1, qf[nt], zero);

        bf16x8 vf[2];
#pragma unroll
        for (int dt = 0; dt < 2; ++dt)
            vf[dt] = *(const bf16x8*)&Vt[(dt*16 + l15)*VT_ST + j0 + quad*8];

#pragma unroll
        for (int s = 0; s < 2; ++s) {
#pragma unroll
            for (int u = 0; u < 2; ++u) {
                const int nt = 2*s + u;
                bf16x4 pk0, pk1;
                float rs = 0.f;
#pragma unroll
                for (int reg = 0; reg < 4; ++reg) {
                    float p = exp2f(st0[nt][reg] + (float)bc[nt][reg]);
                    pk0[reg] = (__bf16)p;  rs += p;
                }
#pragma unroll
                for (int reg = 0; reg < 4; ++reg) {
                    float p = exp2f(st1[nt][reg] + (float)bc[nt][4+reg]);
                    pk1[reg] = (__bf16)p;  rs += p;
                }
                lp[nt] += rs;
                *(bf16x4*)&pw[(u*16 + l15)*PW_ST + quad*4]      = pk0;
                *(bf16x4*)&pw[(u*16 + l15)*PW_ST + 16 + quad*4] = pk1;
            }
#pragma unroll
            for (int u = 0; u < 2; ++u) {
                const int nt = 2*s + u;
                bf16x8 pf = *(const bf16x8*)&pw[(u*16 + l15)*PW_ST + quad*8];
                O[nt][0] = MFMA16(pf, vf[0], O[nt][0]);
                O[nt][1] = MFMA16(pf, vf[1], O[nt][1]);
            }
        }
    }

    // ---- epilogue: reduce l over quads, gate, store bf16
#pragma unroll
    for (int nt = 0; nt < 4; ++nt) {
        lp[nt] += __shfl_xor(lp[nt], 16);
        lp[nt] += __shfl_xor(lp[nt], 32);
    }
#pragma unroll
    for (int nt = 0; nt < 4; ++nt) {
#pragma unroll
        for (int reg = 0; reg < 4; ++reg) {
            const float lsum = __shfl(lp[nt], quad*4 + reg);
            const float inv = 1.f / lsum;
            const size_t pos = rowBase + i0 + nt*16 + quad*4 + reg;
            const __bf16* gp = gateb + pos*128 + h*32 + l15;
            __bf16* op = attb + pos*128 + h*32 + l15;
            op[0]  = (__bf16)(O[nt][0][reg] * inv * (float)gp[0]);
            op[16] = (__bf16)(O[nt][1][reg] * inv * (float)gp[16]);
        }
    }
}

// ---------------- k3: output projection (MFMA) ----------------
__global__ __launch_bounds__(512) void k_out(
    const __bf16* __restrict__ attb, const __bf16* __restrict__ wT,
    const float* __restrict__ bout, float* __restrict__ out)
{
    __shared__ __bf16 As[128*128];
    __shared__ __bf16 Bs[128*128];
    const int t = threadIdx.x;
    const int posBase = blockIdx.x * 128;
    const int srow = t >> 2, skc0 = (t & 3) * 4;

    {
        const __bf16* asrc = attb + (size_t)(posBase + srow)*128;
        const __bf16* bsrc = wT + (size_t)(512 + srow)*128;   // WoutT rows
#pragma unroll
        for (int j = 0; j < 4; ++j) {
            *(bf16x8*)&As[swz(srow, skc0 + j)] = *(const bf16x8*)(asrc + (skc0 + j)*8);
            *(bf16x8*)&Bs[swz(srow, skc0 + j)] = *(const bf16x8*)(bsrc + (skc0 + j)*8);
        }
    }
    __syncthreads();

    const int lane = t & 63, wv = t >> 6;
    const int l15 = lane & 15, quad = lane >> 4;
    const int m0 = wv * 16;

    f32x4 acc[8] = {};
#pragma unroll
    for (int kstep = 0; kstep < 4; ++kstep) {
        bf16x8 aA = *(const bf16x8*)&As[swz(m0 + l15, kstep*4 + quad)];
#pragma unroll
        for (int nt = 0; nt < 8; ++nt) {
            bf16x8 bB = *(const bf16x8*)&Bs[swz(nt*16 + l15, kstep*4 + quad)];
            acc[nt] = MFMA16(aA, bB, acc[nt]);
        }
    }

#pragma unroll
    for (int reg = 0; reg < 4; ++reg) {
        float* op = out + (size_t)(posBase + m0 + quad*4 + reg)*128 + l15;
#pragma unroll
        for (int nt = 0; nt < 8; ++nt)
            op[nt*16] = acc[nt][reg] + bout[nt*16 + l15];
    }
}

extern "C" void kernel_launch(void* const* d_in, const int* in_sizes, int n_in,
                              void* d_out, int out_size, void* d_ws, size_t ws_size,
                              hipStream_t stream) {
    const float* z     = (const float*)d_in[0];
    const float* ln_g  = (const float*)d_in[1];
    const float* ln_b  = (const float*)d_in[2];
    const float* Wqkv  = (const float*)d_in[3];
    const float* Wpair = (const float*)d_in[4];
    const float* Wgate = (const float*)d_in[5];
    const float* bgate = (const float*)d_in[6];
    const float* Wout  = (const float*)d_in[7];
    const float* bout  = (const float*)d_in[8];
    float* out = (float*)d_out;

    __bf16* qkvb  = (__bf16*)d_ws;                        // NPOS*384
    __bf16* attb  = qkvb  + (size_t)NPOS*384;             // NPOS*128
    __bf16* wT    = attb  + (size_t)NPOS*128;             // 640*128
    __bf16* gateb = wT    + (size_t)640*128;              // NPOS*128
    __bf16* biasX = gateb + (size_t)NPOS*128;             // 4*NPOS (packed)

    k_wprep<<<640, 128, 0, stream>>>(Wqkv, Wgate, Wout, wT);
    k_ln_proj<<<800, 512, 0, stream>>>(z, ln_g, ln_b, wT, Wpair, bgate, qkvb, biasX, gateb);
    k_attn<<<dim3(320, 4), 320, 0, stream>>>(qkvb, biasX, gateb, attb);
    k_out<<<800, 512, 0, stream>>>(attb, wT, bout, out);
}